// Round 7
// baseline (92.309 us; speedup 1.0000x reference)
//
#include <hip/hip_runtime.h>
#include <math.h>

typedef __attribute__((ext_vector_type(8))) __bf16 b16x8;
typedef __attribute__((ext_vector_type(4))) float f32x4;

#define GLDS(gp, lp) __builtin_amdgcn_global_load_lds(                         \
    (const __attribute__((address_space(1))) unsigned int*)(gp),               \
    (__attribute__((address_space(3))) unsigned int*)(lp), 16, 0, 0)

#define WAIT_VM2()   asm volatile("s_waitcnt vmcnt(2)" ::: "memory")
#define WAIT_VM0()   asm volatile("s_waitcnt vmcnt(0)" ::: "memory")
#define BAR()        __builtin_amdgcn_s_barrier()

__device__ __forceinline__ unsigned short f2bf(float x) {
    unsigned int v = __float_as_uint(x);
    v += 0x7fffu + ((v >> 16) & 1u);
    return (unsigned short)(v >> 16);
}

// 16-lane sum reduction entirely on the VALU via DPP (no LDS pipe).
__device__ __forceinline__ float red16(float x) {
    int v;
    v = __builtin_amdgcn_update_dpp(0, __float_as_int(x), 0xB1, 0xF, 0xF, true);
    x += __int_as_float(v);
    v = __builtin_amdgcn_update_dpp(0, __float_as_int(x), 0x4E, 0xF, 0xF, true);
    x += __int_as_float(v);
    v = __builtin_amdgcn_update_dpp(0, __float_as_int(x), 0x141, 0xF, 0xF, true);
    x += __int_as_float(v);
    v = __builtin_amdgcn_update_dpp(0, __float_as_int(x), 0x140, 0xF, 0xF, true);
    x += __int_as_float(v);
    return x;
}

// ---------------- repack kernel ----------------
// ws layout: [0, 819200): weights bf16, slot s = tap*2 + ks (tap = kh*5+kw):
//   idx = (s*256 + o)*32 + cgp*8 + j                (ushort index)
//   stored cin = ks*32 + (cgp ^ ((o>>1)&3))*8 + j   (XOR swizzle for LDS banks)
// [819200, 820224): bias_sum fp32 [256]
__global__ __launch_bounds__(256) void repack_w(
    const float* __restrict__ Wt, const float* __restrict__ bias,
    unsigned short* __restrict__ wsw, float* __restrict__ wsb) {
    int idx = blockIdx.x * 256 + threadIdx.x;
    if (idx < 409600) {
        int j    = idx & 7;
        int cgp  = (idx >> 3) & 3;
        int o    = (idx >> 5) & 255;
        int ks   = (idx >> 13) & 1;
        int tap  = idx >> 14;          // 0..24 = kh*5+kw
        int cg   = cgp ^ ((o >> 1) & 3);
        int cin  = ks * 32 + cg * 8 + j;
        int ic = cin >> 4, id = cin & 15;
        float w = Wt[((size_t)(ic * 256 + o) * 16 + id) * 25 + tap];
        wsw[idx] = f2bf(w);
    } else if (idx < 409856) {
        int o = idx - 409600;
        float s = 0.f;
        for (int ic = 0; ic < 4; ++ic) s += bias[ic * 256 + o];
        wsb[o] = s;
    }
}

// ---------------- main kernel ----------------
// Block: 256 threads (4 waves) = one 16x16 spatial tile x 128 outputs (half).
// Grid 128x4 -> 512 blocks = 2 blocks/CU (LDS 75,776 B <= 80KB), giving two
// INDEPENDENT barrier domains per CU: one block's staging/prologue/epilogue
// overlaps the other's MFMA bursts.
// Wave tile: 128 pixels x 64 outs = 8 pixfrags x 4 ofrags (16x16x32 MFMA).
// K loop: 50 steps (25 taps x 2 cin-planes), 8KB weight slot per step,
// 3 buffers, depth-2 prefetch via global_load_lds, counted vmcnt(2)/step.
__global__ __launch_bounds__(256, 2) void caps_mfma(
    const float* __restrict__ u, const unsigned short* __restrict__ wsw,
    const float* __restrict__ wsb, float* __restrict__ out) {

    __shared__ __align__(16) unsigned short su_sh[25600];     // 2 planes x [hy20][hx20][cgp4][j8]
    __shared__ __align__(16) unsigned short sw_sh[3][4096];   // 3 x [o128][cgp4][j8] (8KB slots)

    const int tid  = threadIdx.x;
    const int lane = tid & 63;
    const int wid  = tid >> 6;      // 0..3
    const int wm   = wid >> 1;      // 0..1  pixel-row-group
    const int wn   = wid & 1;       // 0..1  output-col-group
    const int col  = lane & 15;
    const int cg   = lane >> 4;     // 0..3  cin-group (and x-group in C layout)
    const int ybase = wm * 8;

    const int bx  = blockIdx.x;     // 0..127: tile = bx>>1, out-half = bx&1
    const int b   = blockIdx.y;     // 0..3
    const int tile = bx >> 1;
    const int oh  = bx & 1;
    const int ty0 = (tile >> 3) * 16;
    const int tx0 = (tile & 7) * 16;

    // B-frag element offsets (ushorts) within one 8KB weight slot (128 outs)
    int b_elem[4];
    #pragma unroll
    for (int fr = 0; fr < 4; ++fr) {
        int ol = wn * 64 + fr * 16 + col;          // local out 0..127
        int cgp = cg ^ ((ol >> 1) & 3);
        b_elem[fr] = ol * 32 + cgp * 8;
    }

    // A-frag column offsets per kw (ushort index within a row cell)
    int coffs[5];
    #pragma unroll
    for (int kw = 0; kw < 5; ++kw) {
        int hx = col + kw;
        coffs[kw] = hx * 32 + ((cg ^ ((hx >> 1) & 3)) * 8);
    }

    f32x4 acc[8][4];
    #pragma unroll
    for (int f = 0; f < 8; ++f)
        #pragma unroll
        for (int fr = 0; fr < 4; ++fr) acc[f][fr] = (f32x4)0.f;

    auto stage_u = [&](int half) {
        const float* up = u + ((size_t)b * 64 + half * 32) * 16384;
        unsigned short* dstp = su_sh + half * 12800;
        #pragma unroll 1
        for (int i = tid; i < 12800; i += 256) {
            int c = i / 400;                    // cin local 0..31
            int s = i - c * 400;
            int hy = s / 20, hx = s - hy * 20;  // halo coords 0..19
            int gy = ty0 - 2 + hy, gx = tx0 - 2 + hx;
            float v = 0.f;
            if ((unsigned)gy < 128u && (unsigned)gx < 128u)
                v = up[(size_t)c * 16384 + gy * 128 + gx];
            int cgp = (c >> 3) ^ ((hx >> 1) & 3);
            dstp[(hy * 20 + hx) * 32 + cgp * 8 + (c & 7)] = f2bf(v);
        }
    };

    const char* wbase = ((const char*)wsw) + oh * 8192 + wid * 2048 + lane * 16;

    auto stage_w = [&](int slot, int bufI) {
        const char* src = wbase + (size_t)slot * 16384;
        char* dst = ((char*)sw_sh) + bufI * 8192 + wid * 2048;    // wave-uniform dest
        GLDS(src,        dst);
        GLDS(src + 1024, dst + 1024);
    };

    // prologue: stage full u halo (both planes) and weight slots 0,1
    stage_u(0);
    stage_u(1);
    stage_w(0, 0);
    stage_w(1, 1);
    __syncthreads();

    int bufR = 0, bufW = 2;
    #pragma unroll 1
    for (int kh = 0; kh < 5; ++kh) {
        #pragma unroll
        for (int kw = 0; kw < 5; ++kw) {
            #pragma unroll
            for (int ks = 0; ks < 2; ++ks) {
                const int s  = (kh * 5 + kw) * 2 + ks;
                const int sp = (s + 2 > 49) ? 49 : s + 2;   // clamped prefetch slot

                BAR();                           // slot s resident; buf[bufW] free
                const unsigned short* swb = sw_sh[bufR];
                b16x8 bf[4];
                #pragma unroll
                for (int fr = 0; fr < 4; ++fr)
                    bf[fr] = *reinterpret_cast<const b16x8*>(swb + b_elem[fr]);
                stage_w(sp, bufW);               // prefetch slot s+2 (2 GLDS/wave)

                const unsigned short* ap =
                    su_sh + ks * 12800 + (ybase + kh) * 640 + coffs[kw];
                b16x8 a[8];
                #pragma unroll
                for (int f = 0; f < 8; ++f)
                    a[f] = *reinterpret_cast<const b16x8*>(ap + f * 640);

                __builtin_amdgcn_s_setprio(1);
                #pragma unroll
                for (int f = 0; f < 8; ++f)
                    #pragma unroll
                    for (int fr = 0; fr < 4; ++fr)
                        acc[f][fr] = __builtin_amdgcn_mfma_f32_16x16x32_bf16(
                            a[f], bf[fr], acc[f][fr], 0, 0, 0);
                __builtin_amdgcn_s_setprio(0);

                WAIT_VM2();                      // s+1's 2 loads landed; s+2's in flight
                bufR = (bufR == 2) ? 0 : bufR + 1;
                bufW = (bufW == 2) ? 0 : bufW + 1;
            }
        }
    }
    WAIT_VM0();   // drain trailing GLDS before LDS lifetime ends

    // ---------------- epilogue: bias + r-scale + squash (DPP) + float4 store --
    float bsv[4];
    #pragma unroll
    for (int fr = 0; fr < 4; ++fr)
        bsv[fr] = wsb[oh * 128 + wn * 64 + fr * 16 + col];

    const int xg = lane >> 4;   // x-group in C layout
    #pragma unroll
    for (int f = 0; f < 8; ++f) {
        int h = ty0 + ybase + f;
        int rows = min(h + 2, 127) - max(h - 2, 0) + 1;
        #pragma unroll
        for (int p = 0; p < 2; ++p) {
            int oc = oh * 4 + wn * 2 + p;        // global capsule 0..7
            float o0[4], o1[4];
            #pragma unroll
            for (int r = 0; r < 4; ++r) {
                int w = tx0 + xg * 4 + r;
                int colsv = min(w + 2, 127) - max(w - 2, 0) + 1;
                float rs = 1.0f / (8.0f * (float)(rows * colsv));
                float p0 = (acc[f][2 * p][r] + bsv[2 * p]) * rs;
                float p1 = (acc[f][2 * p + 1][r] + bsv[2 * p + 1]) * rs;
                o0[r] = p0; o1[r] = p1;
                float sv = red16(p0 * p0 + p1 * p1);
                float scale = sv / ((1.0f + sv) * sqrtf(sv + 1e-9f));
                o0[r] *= scale; o1[r] *= scale;
            }
            size_t base = ((size_t)((b * 8 + oc) * 32) + col) * 16384
                          + (size_t)h * 128 + tx0 + xg * 4;
            float4 v0 = make_float4(o0[0], o0[1], o0[2], o0[3]);
            float4 v1 = make_float4(o1[0], o1[1], o1[2], o1[3]);
            *reinterpret_cast<float4*>(out + base) = v0;
            *reinterpret_cast<float4*>(out + base + (size_t)16 * 16384) = v1;
        }
    }
}

extern "C" void kernel_launch(void* const* d_in, const int* in_sizes, int n_in,
                              void* d_out, int out_size, void* d_ws, size_t ws_size,
                              hipStream_t stream) {
    const float* u    = (const float*)d_in[0];
    const float* Wt   = (const float*)d_in[1];
    const float* bias = (const float*)d_in[2];
    unsigned short* wsw = (unsigned short*)d_ws;
    float* wsb = (float*)((char*)d_ws + 819200);

    repack_w<<<1601, 256, 0, stream>>>(Wt, bias, wsw, wsb);
    caps_mfma<<<dim3(128, 4), 256, 0, stream>>>(u, wsw, wsb, (float*)d_out);
}

// Round 8
// 67.912 us; speedup vs baseline: 1.3592x; 1.3592x over previous
//
#include <hip/hip_runtime.h>
#include <math.h>

typedef __attribute__((ext_vector_type(8))) __bf16 b16x8;
typedef __attribute__((ext_vector_type(4))) float f32x4;

#define GLDS(gp, lp) __builtin_amdgcn_global_load_lds(                         \
    (const __attribute__((address_space(1))) unsigned int*)(gp),               \
    (__attribute__((address_space(3))) unsigned int*)(lp), 16, 0, 0)

#define WAIT_VM2()   asm volatile("s_waitcnt vmcnt(2)" ::: "memory")
#define WAIT_VM0()   asm volatile("s_waitcnt vmcnt(0)" ::: "memory")
#define BAR()        __builtin_amdgcn_s_barrier()

__device__ __forceinline__ unsigned short f2bf(float x) {
    unsigned int v = __float_as_uint(x);
    v += 0x7fffu + ((v >> 16) & 1u);
    return (unsigned short)(v >> 16);
}

// 16-lane sum reduction entirely on the VALU via DPP (no LDS pipe).
__device__ __forceinline__ float red16(float x) {
    int v;
    v = __builtin_amdgcn_update_dpp(0, __float_as_int(x), 0xB1, 0xF, 0xF, true);
    x += __int_as_float(v);
    v = __builtin_amdgcn_update_dpp(0, __float_as_int(x), 0x4E, 0xF, 0xF, true);
    x += __int_as_float(v);
    v = __builtin_amdgcn_update_dpp(0, __float_as_int(x), 0x141, 0xF, 0xF, true);
    x += __int_as_float(v);
    v = __builtin_amdgcn_update_dpp(0, __float_as_int(x), 0x140, 0xF, 0xF, true);
    x += __int_as_float(v);
    return x;
}

// ---------------- repack kernel ----------------
// ws layout: [0, 819200): weights bf16, natural tap order (tap = kh*5+kw):
//   idx = ((tap*2 + ks)*256 + o)*32 + cgp*8 + j     (ushort index)
//   stored cin = ks*32 + (cgp ^ ((o>>1)&3))*8 + j   (XOR swizzle for LDS banks)
// [819200, 820224): bias_sum fp32 [256]
__global__ __launch_bounds__(256) void repack_w(
    const float* __restrict__ Wt, const float* __restrict__ bias,
    unsigned short* __restrict__ wsw, float* __restrict__ wsb) {
    int idx = blockIdx.x * 256 + threadIdx.x;
    if (idx < 409600) {
        int j    = idx & 7;
        int cgp  = (idx >> 3) & 3;
        int o    = (idx >> 5) & 255;
        int ks   = (idx >> 13) & 1;
        int tap  = idx >> 14;          // 0..24 = kh*5+kw
        int cg   = cgp ^ ((o >> 1) & 3);
        int cin  = ks * 32 + cg * 8 + j;
        int ic = cin >> 4, id = cin & 15;
        float w = Wt[((size_t)(ic * 256 + o) * 16 + id) * 25 + tap];
        wsw[idx] = f2bf(w);
    } else if (idx < 409856) {
        int o = idx - 409600;
        float s = 0.f;
        for (int ic = 0; ic < 4; ++ic) s += bias[ic * 256 + o];
        wsb[o] = s;
    }
}

// ---------------- main kernel ----------------
// Block: 1024 threads (16 waves) = one 16x16 spatial tile x all 256 outputs.
// 1 block/CU (LDS 149.5KB) but now 4 waves/SIMD (needs VGPR<=128, enforced
// by __launch_bounds__(1024,4)) -> latency/barrier-skew hidden by TLP.
// Wave tile: 64 pixels x 64 outs = 4 pixfrags x 4 ofrags (16x16x32 MFMA),
// acc = 64 VGPR. K loop: 25 taps, K=64/tap. Weights triple-buffered,
// depth-2 prefetch via global_load_lds (2/wave/tap), counted vmcnt(2)/tap.
__global__ __launch_bounds__(1024, 4) void caps_mfma(
    const float* __restrict__ u, const unsigned short* __restrict__ wsw,
    const float* __restrict__ wsb, float* __restrict__ out) {

    __shared__ __align__(16) unsigned short su_sh[25600];       // 2 planes x [hy20][hx20][cgp4][j8]
    __shared__ __align__(16) unsigned short sw_sh[3][16384];    // 3 x [ks2][o256][cgp4][j8]

    const int tid  = threadIdx.x;
    const int lane = tid & 63;
    const int wid  = tid >> 6;      // 0..15
    const int wm   = wid >> 2;      // 0..3  pixel-row-group (4 rows each)
    const int wn   = wid & 3;       // 0..3  output-col-group (64 outs each)
    const int col  = lane & 15;
    const int cg   = lane >> 4;     // 0..3  cin-group (and x-group in C layout)
    const int ybase = wm * 4;
    const int obase = wn * 64;

    const int bx  = blockIdx.x;     // 0..63
    const int b   = blockIdx.y;     // 0..3
    const int ty0 = (bx >> 3) * 16;
    const int tx0 = (bx & 7) * 16;

    // B-frag element offsets (ushorts) within one weight plane
    int b_elem[4];
    #pragma unroll
    for (int fr = 0; fr < 4; ++fr) {
        int o = obase + fr * 16 + col;
        int cgp = cg ^ ((o >> 1) & 3);
        b_elem[fr] = o * 32 + cgp * 8;
    }

    // A-frag column offsets per kw (ushort index within a row cell)
    int coffs[5];
    #pragma unroll
    for (int kw = 0; kw < 5; ++kw) {
        int hx = col + kw;
        coffs[kw] = hx * 32 + ((cg ^ ((hx >> 1) & 3)) * 8);
    }

    f32x4 acc[4][4];
    #pragma unroll
    for (int f = 0; f < 4; ++f)
        #pragma unroll
        for (int fr = 0; fr < 4; ++fr) acc[f][fr] = (f32x4)0.f;

    auto stage_u = [&](int half) {
        const float* up = u + ((size_t)b * 64 + half * 32) * 16384;
        unsigned short* dstp = su_sh + half * 12800;
        #pragma unroll 1
        for (int i = tid; i < 12800; i += 1024) {
            int c = i / 400;                    // cin local 0..31
            int s = i - c * 400;
            int hy = s / 20, hx = s - hy * 20;  // halo coords 0..19
            int gy = ty0 - 2 + hy, gx = tx0 - 2 + hx;
            float v = 0.f;
            if ((unsigned)gy < 128u && (unsigned)gx < 128u)
                v = up[(size_t)c * 16384 + gy * 128 + gx];
            int cgp = (c >> 3) ^ ((hx >> 1) & 3);
            dstp[(hy * 20 + hx) * 32 + cgp * 8 + (c & 7)] = f2bf(v);
        }
    };

    const char* wbase = ((const char*)wsw) + wid * 2048 + lane * 16;

    auto stage_w = [&](int slot, int bufI) {
        const char* src = wbase + (size_t)slot * 32768;
        char* dst = ((char*)sw_sh) + bufI * 32768 + wid * 2048;   // wave-uniform dest
        GLDS(src,        dst);
        GLDS(src + 1024, dst + 1024);
    };

    // prologue: stage full u halo (both planes) and weight slots 0,1
    stage_u(0);
    stage_u(1);
    stage_w(0, 0);
    stage_w(1, 1);
    __syncthreads();

    int bufR = 0, bufW = 2;
    #pragma unroll 1
    for (int kh = 0; kh < 5; ++kh) {
        #pragma unroll
        for (int kw = 0; kw < 5; ++kw) {
            const int t  = kh * 5 + kw;
            const int tn = (t + 2 > 24) ? 24 : t + 2;   // clamped prefetch slot

            BAR();                               // slot t resident; buf[bufW] free
            const unsigned short* swb = sw_sh[bufR];
            const unsigned short* ap  = su_sh + (ybase + kh) * 640 + coffs[kw];

            // ---- plane 0 ----
            b16x8 bf[4], a[4];
            #pragma unroll
            for (int fr = 0; fr < 4; ++fr)
                bf[fr] = *reinterpret_cast<const b16x8*>(swb + b_elem[fr]);
            #pragma unroll
            for (int f = 0; f < 4; ++f)
                a[f] = *reinterpret_cast<const b16x8*>(ap + f * 640);
            stage_w(tn, bufW);                   // prefetch slot t+2 (2 GLDS/wave)

            __builtin_amdgcn_s_setprio(1);
            #pragma unroll
            for (int f = 0; f < 4; ++f)
                #pragma unroll
                for (int fr = 0; fr < 4; ++fr)
                    acc[f][fr] = __builtin_amdgcn_mfma_f32_16x16x32_bf16(
                        a[f], bf[fr], acc[f][fr], 0, 0, 0);
            __builtin_amdgcn_s_setprio(0);

            // ---- plane 1 ----
            #pragma unroll
            for (int fr = 0; fr < 4; ++fr)
                bf[fr] = *reinterpret_cast<const b16x8*>(swb + 8192 + b_elem[fr]);
            #pragma unroll
            for (int f = 0; f < 4; ++f)
                a[f] = *reinterpret_cast<const b16x8*>(ap + 12800 + f * 640);

            __builtin_amdgcn_s_setprio(1);
            #pragma unroll
            for (int f = 0; f < 4; ++f)
                #pragma unroll
                for (int fr = 0; fr < 4; ++fr)
                    acc[f][fr] = __builtin_amdgcn_mfma_f32_16x16x32_bf16(
                        a[f], bf[fr], acc[f][fr], 0, 0, 0);
            __builtin_amdgcn_s_setprio(0);

            WAIT_VM2();                          // slot t+1's 2 loads landed; t+2's in flight
            bufR = (bufR == 2) ? 0 : bufR + 1;
            bufW = (bufW == 2) ? 0 : bufW + 1;
        }
    }
    WAIT_VM0();   // drain trailing GLDS before LDS lifetime ends

    // ---------------- epilogue: bias + r-scale + squash (DPP) + float4 store --
    float bsv[4];
    #pragma unroll
    for (int fr = 0; fr < 4; ++fr) bsv[fr] = wsb[obase + fr * 16 + col];

    const int xg = lane >> 4;   // x-group in C layout
    #pragma unroll
    for (int f = 0; f < 4; ++f) {
        int h = ty0 + ybase + f;
        int rows = min(h + 2, 127) - max(h - 2, 0) + 1;
        #pragma unroll
        for (int p = 0; p < 2; ++p) {
            int oc = wn * 2 + p;
            float o0[4], o1[4];
            #pragma unroll
            for (int r = 0; r < 4; ++r) {
                int w = tx0 + xg * 4 + r;
                int colsv = min(w + 2, 127) - max(w - 2, 0) + 1;
                float rs = 1.0f / (8.0f * (float)(rows * colsv));
                float p0 = (acc[f][2 * p][r] + bsv[2 * p]) * rs;
                float p1 = (acc[f][2 * p + 1][r] + bsv[2 * p + 1]) * rs;
                o0[r] = p0; o1[r] = p1;
                float sv = red16(p0 * p0 + p1 * p1);
                float scale = sv / ((1.0f + sv) * sqrtf(sv + 1e-9f));
                o0[r] *= scale; o1[r] *= scale;
            }
            size_t base = ((size_t)((b * 8 + oc) * 32) + col) * 16384
                          + (size_t)h * 128 + tx0 + xg * 4;
            float4 v0 = make_float4(o0[0], o0[1], o0[2], o0[3]);
            float4 v1 = make_float4(o1[0], o1[1], o1[2], o1[3]);
            *reinterpret_cast<float4*>(out + base) = v0;
            *reinterpret_cast<float4*>(out + base + (size_t)16 * 16384) = v1;
        }
    }
}

extern "C" void kernel_launch(void* const* d_in, const int* in_sizes, int n_in,
                              void* d_out, int out_size, void* d_ws, size_t ws_size,
                              hipStream_t stream) {
    const float* u    = (const float*)d_in[0];
    const float* Wt   = (const float*)d_in[1];
    const float* bias = (const float*)d_in[2];
    unsigned short* wsw = (unsigned short*)d_ws;
    float* wsb = (float*)((char*)d_ws + 819200);

    repack_w<<<1601, 256, 0, stream>>>(Wt, bias, wsw, wsb);
    caps_mfma<<<dim3(64, 4), 1024, 0, stream>>>(u, wsw, wsb, (float*)d_out);
}

// Round 9
// 66.476 us; speedup vs baseline: 1.3886x; 1.0216x over previous
//
#include <hip/hip_runtime.h>
#include <math.h>

typedef __attribute__((ext_vector_type(8))) __bf16 b16x8;
typedef __attribute__((ext_vector_type(4))) float f32x4;

#define GLDS(gp, lp) __builtin_amdgcn_global_load_lds(                         \
    (const __attribute__((address_space(1))) unsigned int*)(gp),               \
    (__attribute__((address_space(3))) unsigned int*)(lp), 16, 0, 0)

#define WAIT_VM2()   asm volatile("s_waitcnt vmcnt(2)" ::: "memory")
#define WAIT_VM0()   asm volatile("s_waitcnt vmcnt(0)" ::: "memory")
#define BAR()        __builtin_amdgcn_s_barrier()

__device__ __forceinline__ unsigned short f2bf(float x) {
    unsigned int v = __float_as_uint(x);
    v += 0x7fffu + ((v >> 16) & 1u);
    return (unsigned short)(v >> 16);
}

// 16-lane sum reduction entirely on the VALU via DPP (no LDS pipe).
__device__ __forceinline__ float red16(float x) {
    int v;
    v = __builtin_amdgcn_update_dpp(0, __float_as_int(x), 0xB1, 0xF, 0xF, true);
    x += __int_as_float(v);
    v = __builtin_amdgcn_update_dpp(0, __float_as_int(x), 0x4E, 0xF, 0xF, true);
    x += __int_as_float(v);
    v = __builtin_amdgcn_update_dpp(0, __float_as_int(x), 0x141, 0xF, 0xF, true);
    x += __int_as_float(v);
    v = __builtin_amdgcn_update_dpp(0, __float_as_int(x), 0x140, 0xF, 0xF, true);
    x += __int_as_float(v);
    return x;
}

// ---------------- repack kernel ----------------
// ws layout: [0, 819200): weights bf16 in MAIN-LOOP VISIT ORDER:
//   slot l = kw*10 + ks*5 + kh  (16KB each; conv tap = kh*5+kw, plane ks)
//   idx = (l*256 + o)*32 + cgp*8 + j                (ushort index)
//   stored cin = ks*32 + (cgp ^ ((o>>1)&3))*8 + j   (XOR swizzle for LDS banks)
// [819200, 820224): bias_sum fp32 [256]
__global__ __launch_bounds__(256) void repack_w(
    const float* __restrict__ Wt, const float* __restrict__ bias,
    unsigned short* __restrict__ wsw, float* __restrict__ wsb) {
    int idx = blockIdx.x * 256 + threadIdx.x;
    if (idx < 409600) {
        int j    = idx & 7;
        int cgp  = (idx >> 3) & 3;
        int o    = (idx >> 5) & 255;
        int l    = idx >> 13;          // visit slot 0..49
        int kh   = l % 5;
        int ks   = (l / 5) & 1;
        int kw   = l / 10;
        int tap  = kh * 5 + kw;
        int cg   = cgp ^ ((o >> 1) & 3);
        int cin  = ks * 32 + cg * 8 + j;
        int ic = cin >> 4, id = cin & 15;
        float w = Wt[((size_t)(ic * 256 + o) * 16 + id) * 25 + tap];
        wsw[idx] = f2bf(w);
    } else if (idx < 409856) {
        int o = idx - 409600;
        float s = 0.f;
        for (int ic = 0; ic < 4; ++ic) s += bias[ic * 256 + o];
        wsb[o] = s;
    }
}

// ---------------- main kernel ----------------
// Block: 1024 threads (16 waves) = one 16x16 spatial tile x all 256 outputs.
// Wave tile: 64 pix x 64 outs = 4 pixfrags x 4 ofrags (16x16x32 MFMA).
// Loop: kw outer -> ks (cin plane) -> kh inner; 50 iterations, slot l walks
// the repacked weights sequentially. A-frags in a sliding register window:
// 4 preloaded per (kw,ks), +1 new row per kh (A LDS reads /5).
// Weights: 4 LDS buffers (16KB each), depth-3 prefetch, 1 GLDS/wave/slot,
// counted vmcnt(2) per iteration (never drained in loop).
__global__ __launch_bounds__(1024, 4) void caps_mfma(
    const float* __restrict__ u, const unsigned short* __restrict__ wsw,
    const float* __restrict__ wsb, float* __restrict__ out) {

    __shared__ __align__(16) unsigned short su_sh[25600];       // 2 planes x [hy20][hx20][cgp4][j8]
    __shared__ __align__(16) unsigned short sw_sh[4][8192];     // 4 x [o256][cgp4][j8] (16KB)

    const int tid  = threadIdx.x;
    const int lane = tid & 63;
    const int wid  = tid >> 6;      // 0..15
    const int wm   = wid >> 2;      // 0..3  pixel-row-group (4 rows each)
    const int wn   = wid & 3;       // 0..3  output-col-group (64 outs each)
    const int col  = lane & 15;
    const int cg   = lane >> 4;     // 0..3  cin-group (and x-group in C layout)
    const int ybase = wm * 4;
    const int obase = wn * 64;

    const int bx  = blockIdx.x;     // 0..63
    const int b   = blockIdx.y;     // 0..3
    const int ty0 = (bx >> 3) * 16;
    const int tx0 = (bx & 7) * 16;

    // B-frag element offsets (ushorts) within one weight slot
    int b_elem[4];
    #pragma unroll
    for (int fr = 0; fr < 4; ++fr) {
        int o = obase + fr * 16 + col;
        int cgp = cg ^ ((o >> 1) & 3);
        b_elem[fr] = o * 32 + cgp * 8;
    }

    // A-frag column offsets per kw (ushort index within a row cell)
    int coffs[5];
    #pragma unroll
    for (int kw = 0; kw < 5; ++kw) {
        int hx = col + kw;
        coffs[kw] = hx * 32 + ((cg ^ ((hx >> 1) & 3)) * 8);
    }

    f32x4 acc[4][4];
    #pragma unroll
    for (int f = 0; f < 4; ++f)
        #pragma unroll
        for (int fr = 0; fr < 4; ++fr) acc[f][fr] = (f32x4)0.f;

    auto stage_u = [&](int half) {
        const float* up = u + ((size_t)b * 64 + half * 32) * 16384;
        unsigned short* dstp = su_sh + half * 12800;
        #pragma unroll 1
        for (int i = tid; i < 12800; i += 1024) {
            int c = i / 400;                    // cin local 0..31
            int s = i - c * 400;
            int hy = s / 20, hx = s - hy * 20;  // halo coords 0..19
            int gy = ty0 - 2 + hy, gx = tx0 - 2 + hx;
            float v = 0.f;
            if ((unsigned)gy < 128u && (unsigned)gx < 128u)
                v = up[(size_t)c * 16384 + gy * 128 + gx];
            int cgp = (c >> 3) ^ ((hx >> 1) & 3);
            dstp[(hy * 20 + hx) * 32 + cgp * 8 + (c & 7)] = f2bf(v);
        }
    };

    const char* wbase = ((const char*)wsw) + wid * 1024 + lane * 16;

    auto stage_unit = [&](int slot, int bufI) {
        const char* src = wbase + (size_t)slot * 16384;
        char* dst = ((char*)sw_sh) + bufI * 16384 + wid * 1024;   // wave-uniform dest
        GLDS(src, dst);                                           // 1 GLDS/wave (1KB)
    };

    // prologue: weight slots 0..2 in flight first, then u halo (both planes)
    stage_unit(0, 0);
    stage_unit(1, 1);
    stage_unit(2, 2);
    stage_u(0);
    stage_u(1);
    __syncthreads();              // drains vmcnt -> slots 0..2 and halo resident

    int l = 0;
    #pragma unroll 1
    for (int kw = 0; kw < 5; ++kw) {
        const int coff = coffs[kw];
        #pragma unroll 1
        for (int ks = 0; ks < 2; ++ks) {
            const unsigned short* apb = su_sh + ks * 12800 + ybase * 640 + coff;
            b16x8 aw[8];
            #pragma unroll
            for (int i = 0; i < 4; ++i)
                aw[i] = *reinterpret_cast<const b16x8*>(apb + i * 640);

            #pragma unroll
            for (int kh = 0; kh < 5; ++kh) {
                const int ln = (l + 3 > 49) ? 49 : l + 3;   // clamped prefetch

                BAR();                            // slot l resident; buf[(l+3)&3] free
                const unsigned short* swb = sw_sh[l & 3];
                b16x8 bf[4];
                #pragma unroll
                for (int fr = 0; fr < 4; ++fr)
                    bf[fr] = *reinterpret_cast<const b16x8*>(swb + b_elem[fr]);
                if (kh < 4)                       // extend A window by one row
                    aw[kh + 4] =
                        *reinterpret_cast<const b16x8*>(apb + (kh + 4) * 640);
                stage_unit(ln, (l + 3) & 3);      // prefetch slot l+3

                __builtin_amdgcn_s_setprio(1);
                #pragma unroll
                for (int f = 0; f < 4; ++f)
                    #pragma unroll
                    for (int fr = 0; fr < 4; ++fr)
                        acc[f][fr] = __builtin_amdgcn_mfma_f32_16x16x32_bf16(
                            aw[kh + f], bf[fr], acc[f][fr], 0, 0, 0);
                __builtin_amdgcn_s_setprio(0);

                WAIT_VM2();                       // slot l+1 landed; l+2,l+3 in flight
                ++l;
            }
        }
    }
    WAIT_VM0();   // drain trailing GLDS before LDS lifetime ends

    // ---------------- epilogue: bias + r-scale + squash (DPP) + float4 store --
    float bsv[4];
    #pragma unroll
    for (int fr = 0; fr < 4; ++fr) bsv[fr] = wsb[obase + fr * 16 + col];

    const int xg = lane >> 4;   // x-group in C layout
    #pragma unroll
    for (int f = 0; f < 4; ++f) {
        int h = ty0 + ybase + f;
        int rows = min(h + 2, 127) - max(h - 2, 0) + 1;
        #pragma unroll
        for (int p = 0; p < 2; ++p) {
            int oc = wn * 2 + p;
            float o0[4], o1[4];
            #pragma unroll
            for (int r = 0; r < 4; ++r) {
                int w = tx0 + xg * 4 + r;
                int colsv = min(w + 2, 127) - max(w - 2, 0) + 1;
                float rs = 1.0f / (8.0f * (float)(rows * colsv));
                float p0 = (acc[f][2 * p][r] + bsv[2 * p]) * rs;
                float p1 = (acc[f][2 * p + 1][r] + bsv[2 * p + 1]) * rs;
                o0[r] = p0; o1[r] = p1;
                float sv = red16(p0 * p0 + p1 * p1);
                float scale = sv / ((1.0f + sv) * sqrtf(sv + 1e-9f));
                o0[r] *= scale; o1[r] *= scale;
            }
            size_t base = ((size_t)((b * 8 + oc) * 32) + col) * 16384
                          + (size_t)h * 128 + tx0 + xg * 4;
            float4 v0 = make_float4(o0[0], o0[1], o0[2], o0[3]);
            float4 v1 = make_float4(o1[0], o1[1], o1[2], o1[3]);
            *reinterpret_cast<float4*>(out + base) = v0;
            *reinterpret_cast<float4*>(out + base + (size_t)16 * 16384) = v1;
        }
    }
}

extern "C" void kernel_launch(void* const* d_in, const int* in_sizes, int n_in,
                              void* d_out, int out_size, void* d_ws, size_t ws_size,
                              hipStream_t stream) {
    const float* u    = (const float*)d_in[0];
    const float* Wt   = (const float*)d_in[1];
    const float* bias = (const float*)d_in[2];
    unsigned short* wsw = (unsigned short*)d_ws;
    float* wsb = (float*)((char*)d_ws + 819200);

    repack_w<<<1601, 256, 0, stream>>>(Wt, bias, wsw, wsb);
    caps_mfma<<<dim3(64, 4), 1024, 0, stream>>>(u, wsw, wsb, (float*)d_out);
}